// Round 5
// baseline (408.488 us; speedup 1.0000x reference)
//
#include <hip/hip_runtime.h>
#include <stdint.h>

#define CONF_THR 0.6f
#define IOU_THR  0.45f
#define MAX_WH_F 4096.0f
#define TOPK     1024
#define MAX_DET  300
#define NCLS     80
#define ROW      85
#define APB      128   // anchors per block in K1
#define RING     16    // k_nms register prefetch ring (32 VGPRs - no spill)
#define CAND2    1024  // k_topk stage-2 candidate capacity (global fallback if exceeded)

typedef unsigned int u32;
typedef unsigned long long u64;

__device__ __forceinline__ u32 f2s(float f) {
    u32 b = __float_as_uint(f);
    return b ^ ((u32)((int)b >> 31) | 0x80000000u);
}
__device__ __forceinline__ float s2f(u32 k) {
    u32 b = (k & 0x80000000u) ? (k ^ 0x80000000u) : ~k;
    return __uint_as_float(b);
}

// match-any histogram add: dedup same-digit lanes in the wave (hot-bin safe)
__device__ __forceinline__ void hist_add(u32* hist, u32 d, bool in, int lane) {
    u64 peers = __ballot(in);
#pragma unroll
    for (int bit = 0; bit < 8; ++bit) {
        u64 bb = __ballot((d >> bit) & 1u);
        peers &= ((d >> bit) & 1u) ? bb : ~bb;
    }
    if (in) {
        int leader = (int)(__ffsll((long long)peers) - 1);
        if (lane == leader) atomicAdd(&hist[d], (u32)__popcll(peers));
    }
}

// largest digit d with suffix-sum(hist)[d] >= target; *sh_t = target - sfx[d+1]
__device__ __forceinline__ void suffix_select(const u32* hist, int tid, u32 target,
                                              int* sh_d, u32* sh_t) {
    if (tid < 64) {
        u32 h0 = hist[4 * tid], h1 = hist[4 * tid + 1];
        u32 h2 = hist[4 * tid + 2], h3 = hist[4 * tid + 3];
        u32 s = h0 + h1 + h2 + h3;
        u32 t = s;
#pragma unroll
        for (int off = 1; off < 64; off <<= 1) {
            u32 o = (u32)__shfl_down((int)t, off);
            if (tid + off < 64) t += o;
        }
        u32 S0 = t, S1 = t - h0, S2 = S1 - h1, S3 = S2 - h2, S4 = t - s;
        if (S0 >= target && S1 < target) { *sh_d = 4 * tid;     *sh_t = target - S1; }
        if (S1 >= target && S2 < target) { *sh_d = 4 * tid + 1; *sh_t = target - S2; }
        if (S2 >= target && S3 < target) { *sh_d = 4 * tid + 2; *sh_t = target - S3; }
        if (S3 >= target && S4 < target) { *sh_d = 4 * tid + 3; *sh_t = target - S4; }
    }
}

// ---------------- K1: per-anchor score/cls ----------------
__global__ __launch_bounds__(256) void k_score(const float* __restrict__ pred,
        u32* __restrict__ key, u32* __restrict__ cls, int NA) {
#pragma clang fp contract(off)
    int img = blockIdx.y;
    int a0 = blockIdx.x * APB;
    int count = min(APB, NA - a0);
    if (count <= 0) return;
    size_t baseoff = ((size_t)img * NA + a0) * ROW;
    const float* base = pred + baseoff;
    __shared__ __align__(16) float tile[APB * ROW];
    int nfloat = count * ROW;
    if ((baseoff & 3) == 0) {
        int nvec = nfloat >> 2;
        const float4* b4 = (const float4*)base;
        float4* t4 = (float4*)tile;
        for (int i = threadIdx.x; i < nvec; i += blockDim.x) t4[i] = b4[i];
        for (int i = (nvec << 2) + threadIdx.x; i < nfloat; i += blockDim.x)
            tile[i] = base[i];
    } else {
        for (int i = threadIdx.x; i < nfloat; i += blockDim.x) tile[i] = base[i];
    }
    __syncthreads();
    int t = threadIdx.x;
    if (t < count) {
        const float* r = tile + t * ROW;
        float obj = r[4];
        float maxv = -1.0f; int cl = 0;
        for (int j = 0; j < NCLS; ++j) {
            float v = r[5 + j] * obj;
            if (v > maxv) { maxv = v; cl = j; }   // first-max == jnp.argmax
        }
        bool valid = (obj > CONF_THR) && (maxv > CONF_THR);
        float score = valid ? maxv : -1.0f;
        size_t g = (size_t)img * NA + a0 + t;
        key[g] = f2s(score);
        cls[g] = (u32)cl;
    }
}

// ---------------- K2: exact top-1024 (LDS-staged radix select + bitonic) -----
// v5: stage top-16 key bits in LDS (50.4 KB) -> levels 0/1 from LDS; levels
// 2/3 on the <=CAND2 compacted 16-bit-prefix candidates (global fallback for
// exactness). Global latency rounds: 25 copy + 25 compact + 25 scatter.
__global__ __launch_bounds__(1024) void k_topk(const u32* __restrict__ key,
        const float* __restrict__ pred, const u32* __restrict__ cls,
        u32* __restrict__ top_idx, float* __restrict__ top_score,
        float* __restrict__ boxk, float* __restrict__ nmsbox,
        float* __restrict__ clsf, int NA) {
#pragma clang fp contract(off)
    int img = blockIdx.x;
    const u32* kb = key + (size_t)img * NA;
    __shared__ u32 hist[256];
    __shared__ int sh_d;
    __shared__ u32 sh_t;
    __shared__ u32 gcnt, ccnt;
    struct ShA { unsigned short key16[25216]; u32 cand2[CAND2]; };
    union ShU { ShA a; u64 skey[TOPK]; };
    __shared__ ShU sh;                       // skey overlaps key16 (dead by then)
    int tid = threadIdx.x;
    int lane = tid & 63;
    u64 lanemask = (1ull << lane) - 1ull;
    u32 target = TOPK;

    // ---- pass 1: global -> LDS key16 copy fused with level-0 histogram ----
    if (tid < 256) hist[tid] = 0;
    __syncthreads();
    for (int c0 = 0; c0 < NA; c0 += 1024) {
        int idx = c0 + tid;
        bool inb = idx < NA;
        u32 k = inb ? kb[idx] : 0u;
        if (inb) sh.a.key16[idx] = (unsigned short)(k >> 16);
        hist_add(hist, k >> 24, inb, lane);
    }
    __syncthreads();
    suffix_select(hist, tid, target, &sh_d, &sh_t);
    __syncthreads();
    u32 d0 = (u32)sh_d; target = sh_t;

    // ---- level 1 from LDS key16 ----
    if (tid < 256) hist[tid] = 0;
    __syncthreads();
    for (int c0 = 0; c0 < NA; c0 += 1024) {
        int idx = c0 + tid;
        bool inb = idx < NA;
        u32 v = inb ? (u32)sh.a.key16[idx] : 0u;
        bool in = inb && ((v >> 8) == d0);
        hist_add(hist, v & 0xFFu, in, lane);
    }
    __syncthreads();
    suffix_select(hist, tid, target, &sh_d, &sh_t);
    __syncthreads();
    u32 prefix = (d0 << 8) | (u32)sh_d;      // 16-bit prefix
    target = sh_t;

    // ---- pass 2: compact full keys matching prefix16 into LDS ----
    if (tid == 0) ccnt = 0;
    __syncthreads();
    for (int c0 = 0; c0 < NA; c0 += 1024) {
        int idx = c0 + tid;
        bool inb = idx < NA;
        u32 k = inb ? kb[idx] : 0u;
        bool put = inb && ((k >> 16) == prefix);
        u64 ball = __ballot(put);
        if (ball) {
            int leader = (int)(__ffsll((long long)ball) - 1);
            u32 base = 0;
            if (lane == leader) base = atomicAdd(&ccnt, (u32)__popcll(ball));
            base = __shfl(base, leader);
            u32 pos = base + (u32)__popcll(ball & lanemask);
            if (put && pos < CAND2) sh.a.cand2[pos] = k;
        }
    }
    __syncthreads();
    u32 nc = ccnt;

    // ---- levels 2,3 (LDS candidates; global fallback if nc > CAND2) ----
    for (int level = 2; level < 4; ++level) {
        int shift = 24 - 8 * level;
        if (tid < 256) hist[tid] = 0;
        __syncthreads();
        if (nc <= CAND2) {
            u32 k = (tid < (int)nc) ? sh.a.cand2[tid] : 0u;
            bool in = (tid < (int)nc) &&
                      ((level == 2) || ((k >> (shift + 8)) == prefix));
            hist_add(hist, (k >> shift) & 0xFFu, in, lane);
        } else {
            for (int c0 = 0; c0 < NA; c0 += 1024) {
                int idx = c0 + tid;
                bool inb = idx < NA;
                u32 k = inb ? kb[idx] : 0u;
                bool in = inb && ((k >> (shift + 8)) == prefix);
                hist_add(hist, (k >> shift) & 0xFFu, in, lane);
            }
        }
        __syncthreads();
        suffix_select(hist, tid, target, &sh_d, &sh_t);
        __syncthreads();
        prefix = (prefix << 8) | (u32)sh_d;
        target = sh_t;
    }
    u32 cutv = prefix;
    u32 R = target;                          // ties to take (smallest-index first)
    u32 T = hist[cutv & 0xFFu];              // level-3 bin == exact-dup count of cutv
    if (tid == 0) gcnt = 0;
    __syncthreads();
    bool takeTies = (T == R);
    // barrier-free wave-aggregated scatter (order fixed later by sort)
    for (int c0 = 0; c0 < NA; c0 += 1024) {
        int idx = c0 + tid;
        bool inb = idx < NA;
        u32 k = inb ? kb[idx] : 0u;
        bool put = inb && ((k > cutv) || (takeTies && k == cutv));
        u64 ball = __ballot(put);
        if (ball) {
            int leader = (int)(__ffsll((long long)ball) - 1);
            u32 base = 0;
            if (lane == leader) base = atomicAdd(&gcnt, (u32)__popcll(ball));
            base = __shfl(base, leader);
            if (put)
                sh.skey[base + (u32)__popcll(ball & lanemask)] =
                    ((u64)k << 32) | (u64)(u32)(NA - 1 - idx);
        }
    }
    __syncthreads();
    if (!takeTies) {
        // exact path: R smallest-index ties, single wave, sequential ranks
        u32 G = gcnt;                        // == TOPK - R
        if (tid < 64) {
            u32 cnt = 0;
            for (int c0 = 0; c0 < NA; c0 += 64) {
                int idx = c0 + tid;
                bool ist = (idx < NA) && (kb[idx] == cutv);
                u64 ball = __ballot(ist);
                u32 rank = cnt + (u32)__popcll(ball & lanemask);
                if (ist && rank < R)
                    sh.skey[G + rank] = ((u64)cutv << 32) | (u64)(u32)(NA - 1 - idx);
                cnt += (u32)__popcll(ball);
                if (cnt >= R) break;
            }
        }
        __syncthreads();
    }
    // bitonic sort, descending by (score, then smaller idx first).
    // j<64 pairs stay inside one 64-thread wave -> lockstep, no barrier needed.
    int jprev = 0;
    for (int k2 = 2; k2 <= TOPK; k2 <<= 1) {
        for (int j = k2 >> 1; j > 0; j >>= 1) {
            if (j >= 64 || jprev >= 64) __syncthreads();
            int i = tid, ixj = i ^ j;
            if (ixj > i) {
                u64 a = sh.skey[i], b = sh.skey[ixj];
                bool desc = ((i & k2) == 0);
                if ((a < b) == desc) { sh.skey[i] = b; sh.skey[ixj] = a; }
            }
            jprev = j;
        }
    }
    __syncthreads();
    u64 kk = sh.skey[tid];
    u32 aidx = (u32)(NA - 1) - (u32)(kk & 0xFFFFFFFFull);
    float sc = s2f((u32)(kk >> 32));
    int g = img * TOPK + tid;
    top_idx[g] = aidx;
    top_score[g] = sc;
    // fused k_prep
    const float* r = pred + ((size_t)img * NA + aidx) * ROW;
    float cx = r[0], cy = r[1], w4 = r[2], h4 = r[3];
    float hw = w4 * 0.5f, hh = h4 * 0.5f;
    float x1 = cx - hw, y1 = cy - hh, x2 = cx + hw, y2 = cy + hh;
    u32 c = cls[(size_t)img * NA + aidx];
    float off = (float)c * MAX_WH_F;
    boxk[g * 4 + 0] = x1; boxk[g * 4 + 1] = y1;
    boxk[g * 4 + 2] = x2; boxk[g * 4 + 3] = y2;
    nmsbox[g * 4 + 0] = x1 + off; nmsbox[g * 4 + 1] = y1 + off;
    nmsbox[g * 4 + 2] = x2 + off; nmsbox[g * 4 + 3] = y2 + off;
    clsf[g] = (float)c;
}

// ---------------- K4: 1024x1024 IoU suppression bitmask ----------------
__global__ __launch_bounds__(1024) void k_mask(const float* __restrict__ nmsbox,
        u64* __restrict__ mask) {
#pragma clang fp contract(off)
    int img = blockIdx.y;
    __shared__ float bx[TOPK + 32], by[TOPK + 32], bX[TOPK + 32], bY[TOPK + 32], ar[TOPK + 32];
    int tid = threadIdx.x;
    {
        const float4* nb = (const float4*)(nmsbox + (size_t)img * TOPK * 4);
        float4 b = nb[tid];
        int pi = tid + (tid >> 5);
        bx[pi] = b.x; by[pi] = b.y; bX[pi] = b.z; bY[pi] = b.w;
        ar[pi] = (b.z - b.x) * (b.w - b.y);
    }
    __syncthreads();
    int i = blockIdx.x * 64 + (tid >> 4);
    int w = tid & 15;
    int pi = i + (i >> 5);
    float ax = bx[pi], ay = by[pi], aX = bX[pi], aY = bY[pi], aa = ar[pi];
    u64 bits = 0;
    for (int jj = 0; jj < 64; ++jj) {
        int j = (w << 6) + jj;
        if (j > i) {
            int pj = j + (j >> 5);
            float ltx = fmaxf(ax, bx[pj]);
            float lty = fmaxf(ay, by[pj]);
            float rbx = fminf(aX, bX[pj]);
            float rby = fminf(aY, bY[pj]);
            float ww = fmaxf(rbx - ltx, 0.0f);
            float hh = fmaxf(rby - lty, 0.0f);
            float inter = ww * hh;
            float denom = ((aa + ar[pj]) - inter) + 1e-9f;  // exact np expr order
            float iou = inter / denom;
            if (iou > IOU_THR) bits |= (1ull << jj);
        }
    }
    mask[((size_t)img * TOPK + i) * 16 + w] = bits;
}

// ---------------- K5: greedy NMS (wave 0) + fused output (all 16 waves) ------
__global__ __launch_bounds__(1024) void k_nms(const u64* __restrict__ mask,
        const float* __restrict__ top_score, const u32* __restrict__ top_idx,
        const float* __restrict__ boxk, const float* __restrict__ clsf,
        const float* __restrict__ logits, float* __restrict__ out,
        u32* __restrict__ dummy, int NA, int B) {
    __shared__ u32 s_nvalid;
    __shared__ u64 keepw[16];
    __shared__ u32 s_sel[MAX_DET];
    __shared__ u32 s_cnt;
    int img = blockIdx.x;
    int tid = threadIdx.x;
    int wid = tid >> 6;
    int lane = tid & 63;
    if (tid == 0) s_nvalid = 0;
    if (tid < 16) keepw[tid] = 0;
    __syncthreads();
    {
        float s = top_score[img * TOPK + tid];
        u64 b = __ballot(s > CONF_THR);
        if (lane == 0) atomicAdd(&s_nvalid, (u32)__popcll(b));
    }
    __syncthreads();
    const u64* mrow = mask + (size_t)img * TOPK * 16;
    if (tid >= 64) {
        // waves 1-15: pull the 128 KB mask into this CU's L1/local L2
        const uint4* m16 = (const uint4*)mrow;          // 8192 vec16
        u32 acc = 0;
        for (int i = tid - 64; i < 8192; i += 960) {
            uint4 v = m16[i];
            acc ^= v.x ^ v.y ^ v.z ^ v.w;
        }
        if (acc == 0xDEADBEEFu) *dummy = acc;           // keep loads alive
    } else {
        // wave 0: serial greedy reduction (16-deep no-spill register ring)
        int nvalid = (int)s_nvalid;
        bool ld = lane < 16;
        u64 rem = 0;                       // lane w<16 owns suppressed word w
        u64 pf[RING];
#pragma unroll
        for (int k = 0; k < RING; ++k)
            pf[k] = ld ? mrow[(size_t)k * 16 + lane] : 0ull;
        int nblk = (nvalid + 63) >> 6;
        int kept_total = 0;
        for (int blk = 0; blk < nblk; ++blk) {
            u64 kw = 0;
            int base = blk << 6;
#pragma unroll 16
            for (int t = 0; t < 64; ++t) {
                int i = base + t;
                u64 roww = pf[i & (RING - 1)];
                int nx = i + RING;
                pf[i & (RING - 1)] = (ld && nx < TOPK) ? mrow[(size_t)nx * 16 + lane] : 0ull;
                bool notsup = (lane == (i >> 6)) && !((rem >> (i & 63)) & 1ull);
                if (__ballot(notsup) != 0ull) {            // wave-uniform keep
                    rem |= roww;                           // roww has only bits j>i
                    kw |= (1ull << t);
                }
            }
            int over = nvalid - base;
            if (over < 64) kw &= (over <= 0) ? 0ull : ((1ull << over) - 1ull);
            if (lane == 0) keepw[blk] = kw;
            kept_total += (int)__popcll(kw);
            if (kept_total >= MAX_DET) break;              // rest can't affect first 300
        }
        // extract first <=300 kept slots into LDS
        if (lane < 16) {
            u64 kw = keepw[lane];
            u32 rank = 0;
            for (int m = 0; m < 16; ++m)
                if (m < lane) rank += (u32)__popcll(keepw[m]);
            while (kw) {
                int b = (int)__ffsll((long long)kw) - 1;
                if (rank < MAX_DET) s_sel[rank] = (u32)((lane << 6) + b);
                ++rank;
                kw &= kw - 1;
            }
        }
        if (lane == 0) s_cnt = (u32)min(kept_total, MAX_DET);
    }
    __syncthreads();
    // fused output: all 16 waves write det/valid/logits (d_out is re-poisoned)
    u32 K = s_cnt;
    for (int t = wid; t < MAX_DET; t += 16) {
        bool v = (u32)t < K;
        int slot = v ? (int)s_sel[t] : 0;
        int g = img * TOPK + slot;
        u32 aidx = top_idx[g];
        size_t detoff = ((size_t)img * MAX_DET + t) * 6;
        size_t voff = (size_t)B * MAX_DET * 6 + (size_t)img * MAX_DET + t;
        size_t loff = (size_t)B * MAX_DET * 7 + ((size_t)img * MAX_DET + t) * NCLS;
        const float* lrow = logits + ((size_t)img * NA + aidx) * NCLS;
        out[loff + lane] = v ? lrow[lane] : 0.0f;
        int l2 = lane + 64;
        if (lane < 16)       out[loff + l2] = v ? lrow[l2] : 0.0f;
        else if (lane < 20)  out[detoff + (lane - 16)] = v ? boxk[(size_t)g * 4 + (lane - 16)] : 0.0f;
        else if (lane == 20) out[detoff + 4] = v ? top_score[g] : 0.0f;
        else if (lane == 21) out[detoff + 5] = v ? clsf[g] : 0.0f;
        else if (lane == 22) out[voff] = v ? 1.0f : 0.0f;
    }
}

extern "C" void kernel_launch(void* const* d_in, const int* in_sizes, int n_in,
                              void* d_out, int out_size, void* d_ws, size_t ws_size,
                              hipStream_t stream) {
    const float* pred = (const float*)d_in[0];
    const float* logits = (const float*)d_in[1];
    float* out = (float*)d_out;
    const int B = out_size / (MAX_DET * (6 + 1 + NCLS));   // 16
    const int NA = in_sizes[0] / (B * ROW);                // 25200

    char* p = (char*)d_ws;
    auto alloc = [&](size_t bytes) -> void* {
        void* r = (void*)p;
        p += (bytes + 255) & ~(size_t)255;
        return r;
    };
    u32* key       = (u32*)alloc((size_t)B * NA * 4);
    u32* cls       = (u32*)alloc((size_t)B * NA * 4);
    u32* top_idx   = (u32*)alloc((size_t)B * TOPK * 4);
    float* top_scr = (float*)alloc((size_t)B * TOPK * 4);
    float* boxk    = (float*)alloc((size_t)B * TOPK * 16);
    float* nmsbox  = (float*)alloc((size_t)B * TOPK * 16);
    float* clsf    = (float*)alloc((size_t)B * TOPK * 4);
    u64* mask      = (u64*)alloc((size_t)B * TOPK * 16 * 8);
    u32* dummy     = (u32*)alloc(256);

    k_score<<<dim3((NA + APB - 1) / APB, B), 256, 0, stream>>>(pred, key, cls, NA);
    k_topk<<<dim3(B), 1024, 0, stream>>>(key, pred, cls, top_idx, top_scr,
                                         boxk, nmsbox, clsf, NA);
    k_mask<<<dim3(TOPK / 64, B), 1024, 0, stream>>>(nmsbox, mask);
    k_nms<<<dim3(B), 1024, 0, stream>>>(mask, top_scr, top_idx, boxk, clsf,
                                        logits, out, dummy, NA, B);
}

// Round 6
// 408.082 us; speedup vs baseline: 1.0010x; 1.0010x over previous
//
#include <hip/hip_runtime.h>
#include <stdint.h>

#define CONF_THR 0.6f
#define IOU_THR  0.45f
#define MAX_WH_F 4096.0f
#define TOPK     1024
#define MAX_DET  300
#define NCLS     80
#define ROW      85
#define APB      128   // anchors per block in K1
#define RING     16    // k_nms prefetch depth (16 NAMED u64 regs - cannot spill)
#define CAND2    1024  // k_topk stage-2 candidate capacity (global fallback if exceeded)

typedef unsigned int u32;
typedef unsigned long long u64;

__device__ __forceinline__ u32 f2s(float f) {
    u32 b = __float_as_uint(f);
    return b ^ ((u32)((int)b >> 31) | 0x80000000u);
}
__device__ __forceinline__ float s2f(u32 k) {
    u32 b = (k & 0x80000000u) ? (k ^ 0x80000000u) : ~k;
    return __uint_as_float(b);
}

// match-any histogram add: dedup same-digit lanes in the wave (hot-bin safe)
__device__ __forceinline__ void hist_add(u32* hist, u32 d, bool in, int lane) {
    u64 peers = __ballot(in);
#pragma unroll
    for (int bit = 0; bit < 8; ++bit) {
        u64 bb = __ballot((d >> bit) & 1u);
        peers &= ((d >> bit) & 1u) ? bb : ~bb;
    }
    if (in) {
        int leader = (int)(__ffsll((long long)peers) - 1);
        if (lane == leader) atomicAdd(&hist[d], (u32)__popcll(peers));
    }
}

// largest digit d with suffix-sum(hist)[d] >= target; *sh_t = target - sfx[d+1]
__device__ __forceinline__ void suffix_select(const u32* hist, int tid, u32 target,
                                              int* sh_d, u32* sh_t) {
    if (tid < 64) {
        u32 h0 = hist[4 * tid], h1 = hist[4 * tid + 1];
        u32 h2 = hist[4 * tid + 2], h3 = hist[4 * tid + 3];
        u32 s = h0 + h1 + h2 + h3;
        u32 t = s;
#pragma unroll
        for (int off = 1; off < 64; off <<= 1) {
            u32 o = (u32)__shfl_down((int)t, off);
            if (tid + off < 64) t += o;
        }
        u32 S0 = t, S1 = t - h0, S2 = S1 - h1, S3 = S2 - h2, S4 = t - s;
        if (S0 >= target && S1 < target) { *sh_d = 4 * tid;     *sh_t = target - S1; }
        if (S1 >= target && S2 < target) { *sh_d = 4 * tid + 1; *sh_t = target - S2; }
        if (S2 >= target && S3 < target) { *sh_d = 4 * tid + 2; *sh_t = target - S3; }
        if (S3 >= target && S4 < target) { *sh_d = 4 * tid + 3; *sh_t = target - S4; }
    }
}

// ---------------- K1: per-anchor score/cls ----------------
__global__ __launch_bounds__(256) void k_score(const float* __restrict__ pred,
        u32* __restrict__ key, u32* __restrict__ cls, int NA) {
#pragma clang fp contract(off)
    int img = blockIdx.y;
    int a0 = blockIdx.x * APB;
    int count = min(APB, NA - a0);
    if (count <= 0) return;
    size_t baseoff = ((size_t)img * NA + a0) * ROW;
    const float* base = pred + baseoff;
    __shared__ __align__(16) float tile[APB * ROW];
    int nfloat = count * ROW;
    if ((baseoff & 3) == 0) {
        int nvec = nfloat >> 2;
        const float4* b4 = (const float4*)base;
        float4* t4 = (float4*)tile;
        for (int i = threadIdx.x; i < nvec; i += blockDim.x) t4[i] = b4[i];
        for (int i = (nvec << 2) + threadIdx.x; i < nfloat; i += blockDim.x)
            tile[i] = base[i];
    } else {
        for (int i = threadIdx.x; i < nfloat; i += blockDim.x) tile[i] = base[i];
    }
    __syncthreads();
    int t = threadIdx.x;
    if (t < count) {
        const float* r = tile + t * ROW;
        float obj = r[4];
        float maxv = -1.0f; int cl = 0;
        for (int j = 0; j < NCLS; ++j) {
            float v = r[5 + j] * obj;
            if (v > maxv) { maxv = v; cl = j; }   // first-max == jnp.argmax
        }
        bool valid = (obj > CONF_THR) && (maxv > CONF_THR);
        float score = valid ? maxv : -1.0f;
        size_t g = (size_t)img * NA + a0 + t;
        key[g] = f2s(score);
        cls[g] = (u32)cl;
    }
}

// ---------------- K2: exact top-1024 (LDS-staged radix select + bitonic) -----
__global__ __launch_bounds__(1024) void k_topk(const u32* __restrict__ key,
        const float* __restrict__ pred, const u32* __restrict__ cls,
        u32* __restrict__ top_idx, float* __restrict__ top_score,
        float* __restrict__ boxk, float* __restrict__ nmsbox,
        float* __restrict__ clsf, int NA) {
#pragma clang fp contract(off)
    int img = blockIdx.x;
    const u32* kb = key + (size_t)img * NA;
    __shared__ u32 hist[256];
    __shared__ int sh_d;
    __shared__ u32 sh_t;
    __shared__ u32 gcnt, ccnt;
    struct ShA { unsigned short key16[25216]; u32 cand2[CAND2]; };
    union ShU { ShA a; u64 skey[TOPK]; };
    __shared__ ShU sh;                       // skey overlaps key16 (dead by then)
    int tid = threadIdx.x;
    int lane = tid & 63;
    u64 lanemask = (1ull << lane) - 1ull;
    u32 target = TOPK;

    // ---- pass 1: global -> LDS key16 copy fused with level-0 histogram ----
    if (tid < 256) hist[tid] = 0;
    __syncthreads();
    for (int c0 = 0; c0 < NA; c0 += 1024) {
        int idx = c0 + tid;
        bool inb = idx < NA;
        u32 k = inb ? kb[idx] : 0u;
        if (inb) sh.a.key16[idx] = (unsigned short)(k >> 16);
        hist_add(hist, k >> 24, inb, lane);
    }
    __syncthreads();
    suffix_select(hist, tid, target, &sh_d, &sh_t);
    __syncthreads();
    u32 d0 = (u32)sh_d; target = sh_t;

    // ---- level 1 from LDS key16 ----
    if (tid < 256) hist[tid] = 0;
    __syncthreads();
    for (int c0 = 0; c0 < NA; c0 += 1024) {
        int idx = c0 + tid;
        bool inb = idx < NA;
        u32 v = inb ? (u32)sh.a.key16[idx] : 0u;
        bool in = inb && ((v >> 8) == d0);
        hist_add(hist, v & 0xFFu, in, lane);
    }
    __syncthreads();
    suffix_select(hist, tid, target, &sh_d, &sh_t);
    __syncthreads();
    u32 prefix = (d0 << 8) | (u32)sh_d;      // 16-bit prefix
    target = sh_t;

    // ---- pass 2: compact full keys matching prefix16 into LDS ----
    if (tid == 0) ccnt = 0;
    __syncthreads();
    for (int c0 = 0; c0 < NA; c0 += 1024) {
        int idx = c0 + tid;
        bool inb = idx < NA;
        u32 k = inb ? kb[idx] : 0u;
        bool put = inb && ((k >> 16) == prefix);
        u64 ball = __ballot(put);
        if (ball) {
            int leader = (int)(__ffsll((long long)ball) - 1);
            u32 base = 0;
            if (lane == leader) base = atomicAdd(&ccnt, (u32)__popcll(ball));
            base = __shfl(base, leader);
            u32 pos = base + (u32)__popcll(ball & lanemask);
            if (put && pos < CAND2) sh.a.cand2[pos] = k;
        }
    }
    __syncthreads();
    u32 nc = ccnt;

    // ---- levels 2,3 (LDS candidates; global fallback if nc > CAND2) ----
    for (int level = 2; level < 4; ++level) {
        int shift = 24 - 8 * level;
        if (tid < 256) hist[tid] = 0;
        __syncthreads();
        if (nc <= CAND2) {
            u32 k = (tid < (int)nc) ? sh.a.cand2[tid] : 0u;
            bool in = (tid < (int)nc) &&
                      ((level == 2) || ((k >> (shift + 8)) == prefix));
            hist_add(hist, (k >> shift) & 0xFFu, in, lane);
        } else {
            for (int c0 = 0; c0 < NA; c0 += 1024) {
                int idx = c0 + tid;
                bool inb = idx < NA;
                u32 k = inb ? kb[idx] : 0u;
                bool in = inb && ((k >> (shift + 8)) == prefix);
                hist_add(hist, (k >> shift) & 0xFFu, in, lane);
            }
        }
        __syncthreads();
        suffix_select(hist, tid, target, &sh_d, &sh_t);
        __syncthreads();
        prefix = (prefix << 8) | (u32)sh_d;
        target = sh_t;
    }
    u32 cutv = prefix;
    u32 R = target;                          // ties to take (smallest-index first)
    u32 T = hist[cutv & 0xFFu];              // level-3 bin == exact-dup count of cutv
    if (tid == 0) gcnt = 0;
    __syncthreads();
    bool takeTies = (T == R);
    // barrier-free wave-aggregated scatter (order fixed later by sort)
    for (int c0 = 0; c0 < NA; c0 += 1024) {
        int idx = c0 + tid;
        bool inb = idx < NA;
        u32 k = inb ? kb[idx] : 0u;
        bool put = inb && ((k > cutv) || (takeTies && k == cutv));
        u64 ball = __ballot(put);
        if (ball) {
            int leader = (int)(__ffsll((long long)ball) - 1);
            u32 base = 0;
            if (lane == leader) base = atomicAdd(&gcnt, (u32)__popcll(ball));
            base = __shfl(base, leader);
            if (put)
                sh.skey[base + (u32)__popcll(ball & lanemask)] =
                    ((u64)k << 32) | (u64)(u32)(NA - 1 - idx);
        }
    }
    __syncthreads();
    if (!takeTies) {
        // exact path: R smallest-index ties, single wave, sequential ranks
        u32 G = gcnt;                        // == TOPK - R
        if (tid < 64) {
            u32 cnt = 0;
            for (int c0 = 0; c0 < NA; c0 += 64) {
                int idx = c0 + tid;
                bool ist = (idx < NA) && (kb[idx] == cutv);
                u64 ball = __ballot(ist);
                u32 rank = cnt + (u32)__popcll(ball & lanemask);
                if (ist && rank < R)
                    sh.skey[G + rank] = ((u64)cutv << 32) | (u64)(u32)(NA - 1 - idx);
                cnt += (u32)__popcll(ball);
                if (cnt >= R) break;
            }
        }
        __syncthreads();
    }
    // bitonic sort, descending by (score, then smaller idx first).
    // j<64 pairs stay inside one 64-thread wave -> lockstep, no barrier needed.
    int jprev = 0;
    for (int k2 = 2; k2 <= TOPK; k2 <<= 1) {
        for (int j = k2 >> 1; j > 0; j >>= 1) {
            if (j >= 64 || jprev >= 64) __syncthreads();
            int i = tid, ixj = i ^ j;
            if (ixj > i) {
                u64 a = sh.skey[i], b = sh.skey[ixj];
                bool desc = ((i & k2) == 0);
                if ((a < b) == desc) { sh.skey[i] = b; sh.skey[ixj] = a; }
            }
            jprev = j;
        }
    }
    __syncthreads();
    u64 kk = sh.skey[tid];
    u32 aidx = (u32)(NA - 1) - (u32)(kk & 0xFFFFFFFFull);
    float sc = s2f((u32)(kk >> 32));
    int g = img * TOPK + tid;
    top_idx[g] = aidx;
    top_score[g] = sc;
    // fused k_prep
    const float* r = pred + ((size_t)img * NA + aidx) * ROW;
    float cx = r[0], cy = r[1], w4 = r[2], h4 = r[3];
    float hw = w4 * 0.5f, hh = h4 * 0.5f;
    float x1 = cx - hw, y1 = cy - hh, x2 = cx + hw, y2 = cy + hh;
    u32 c = cls[(size_t)img * NA + aidx];
    float off = (float)c * MAX_WH_F;
    boxk[g * 4 + 0] = x1; boxk[g * 4 + 1] = y1;
    boxk[g * 4 + 2] = x2; boxk[g * 4 + 3] = y2;
    nmsbox[g * 4 + 0] = x1 + off; nmsbox[g * 4 + 1] = y1 + off;
    nmsbox[g * 4 + 2] = x2 + off; nmsbox[g * 4 + 3] = y2 + off;
    clsf[g] = (float)c;
}

// ---------------- K4: 1024x1024 IoU suppression bitmask ----------------
__global__ __launch_bounds__(1024) void k_mask(const float* __restrict__ nmsbox,
        u64* __restrict__ mask) {
#pragma clang fp contract(off)
    int img = blockIdx.y;
    __shared__ float bx[TOPK + 32], by[TOPK + 32], bX[TOPK + 32], bY[TOPK + 32], ar[TOPK + 32];
    int tid = threadIdx.x;
    {
        const float4* nb = (const float4*)(nmsbox + (size_t)img * TOPK * 4);
        float4 b = nb[tid];
        int pi = tid + (tid >> 5);
        bx[pi] = b.x; by[pi] = b.y; bX[pi] = b.z; bY[pi] = b.w;
        ar[pi] = (b.z - b.x) * (b.w - b.y);
    }
    __syncthreads();
    int i = blockIdx.x * 64 + (tid >> 4);
    int w = tid & 15;
    int pi = i + (i >> 5);
    float ax = bx[pi], ay = by[pi], aX = bX[pi], aY = bY[pi], aa = ar[pi];
    u64 bits = 0;
    for (int jj = 0; jj < 64; ++jj) {
        int j = (w << 6) + jj;
        if (j > i) {
            int pj = j + (j >> 5);
            float ltx = fmaxf(ax, bx[pj]);
            float lty = fmaxf(ay, by[pj]);
            float rbx = fminf(aX, bX[pj]);
            float rby = fminf(aY, bY[pj]);
            float ww = fmaxf(rbx - ltx, 0.0f);
            float hh = fmaxf(rby - lty, 0.0f);
            float inter = ww * hh;
            float denom = ((aa + ar[pj]) - inter) + 1e-9f;  // exact np expr order
            float iou = inter / denom;
            if (iou > IOU_THR) bits |= (1ull << jj);
        }
    }
    mask[((size_t)img * TOPK + i) * 16 + w] = bits;
}

// ---------------- K5: greedy NMS (wave 0) + fused output (all 16 waves) ------
// Ring = 16 NAMED u64 registers + fully macro-unrolled 64-step block body.
// R4/R5 bug: pf[i&15] with runtime blk loop -> LLVM lowered the private array
// to scratch (VGPR_Count=24 < 32 needed) -> ~190-500 cyc/iter scratch chain.
// Named regs with literal T make spilling impossible; i>>6==blk (owner bool),
// i&63==T (literal shift).
__global__ __launch_bounds__(1024) void k_nms(const u64* __restrict__ mask,
        const float* __restrict__ top_score, const u32* __restrict__ top_idx,
        const float* __restrict__ boxk, const float* __restrict__ clsf,
        const float* __restrict__ logits, float* __restrict__ out,
        u32* __restrict__ dummy, int NA, int B) {
    __shared__ u32 s_nvalid;
    __shared__ u64 keepw[16];
    __shared__ u32 s_sel[MAX_DET];
    __shared__ u32 s_cnt;
    int img = blockIdx.x;
    int tid = threadIdx.x;
    int wid = tid >> 6;
    int lane = tid & 63;
    if (tid == 0) s_nvalid = 0;
    if (tid < 16) keepw[tid] = 0;
    __syncthreads();
    {
        float s = top_score[img * TOPK + tid];
        u64 b = __ballot(s > CONF_THR);
        if (lane == 0) atomicAdd(&s_nvalid, (u32)__popcll(b));
    }
    __syncthreads();
    const u64* mrow = mask + (size_t)img * TOPK * 16;
    if (tid >= 64) {
        // waves 1-15: pull the 128 KB mask into this CU's L1/local L2
        const uint4* m16 = (const uint4*)mrow;          // 8192 vec16
        u32 acc = 0;
        for (int i = tid - 64; i < 8192; i += 960) {
            uint4 v = m16[i];
            acc ^= v.x ^ v.y ^ v.z ^ v.w;
        }
        if (acc == 0xDEADBEEFu) *dummy = acc;           // keep loads alive
    } else {
        // wave 0: serial greedy reduction
        int nvalid = (int)s_nvalid;
        bool ld = lane < 16;
        u64 rem = 0;                       // lane w<16 owns suppressed word w
        u64 p0  = ld ? mrow[  0 * 16 + lane] : 0ull;
        u64 p1  = ld ? mrow[  1 * 16 + lane] : 0ull;
        u64 p2  = ld ? mrow[  2 * 16 + lane] : 0ull;
        u64 p3  = ld ? mrow[  3 * 16 + lane] : 0ull;
        u64 p4  = ld ? mrow[  4 * 16 + lane] : 0ull;
        u64 p5  = ld ? mrow[  5 * 16 + lane] : 0ull;
        u64 p6  = ld ? mrow[  6 * 16 + lane] : 0ull;
        u64 p7  = ld ? mrow[  7 * 16 + lane] : 0ull;
        u64 p8  = ld ? mrow[  8 * 16 + lane] : 0ull;
        u64 p9  = ld ? mrow[  9 * 16 + lane] : 0ull;
        u64 p10 = ld ? mrow[ 10 * 16 + lane] : 0ull;
        u64 p11 = ld ? mrow[ 11 * 16 + lane] : 0ull;
        u64 p12 = ld ? mrow[ 12 * 16 + lane] : 0ull;
        u64 p13 = ld ? mrow[ 13 * 16 + lane] : 0ull;
        u64 p14 = ld ? mrow[ 14 * 16 + lane] : 0ull;
        u64 p15 = ld ? mrow[ 15 * 16 + lane] : 0ull;
        int nblk = (nvalid + 63) >> 6;
        int kept_total = 0;
        for (int blk = 0; blk < nblk; ++blk) {
            u64 kw = 0;
            int base = blk << 6;
            bool owner = (lane == blk);
#define NMS_STEP(T, PV) { \
            u64 roww = PV; \
            int nx = base + (T) + RING; \
            PV = (ld && nx < TOPK) ? mrow[(size_t)nx * 16 + lane] : 0ull; \
            bool notsup = owner && !((rem >> (T)) & 1ull); \
            if (__ballot(notsup) != 0ull) { rem |= roww; kw |= (1ull << (T)); } }
#define NMS_STEP16(BB) \
            NMS_STEP((BB)+ 0, p0 ) NMS_STEP((BB)+ 1, p1 ) NMS_STEP((BB)+ 2, p2 ) NMS_STEP((BB)+ 3, p3 ) \
            NMS_STEP((BB)+ 4, p4 ) NMS_STEP((BB)+ 5, p5 ) NMS_STEP((BB)+ 6, p6 ) NMS_STEP((BB)+ 7, p7 ) \
            NMS_STEP((BB)+ 8, p8 ) NMS_STEP((BB)+ 9, p9 ) NMS_STEP((BB)+10, p10) NMS_STEP((BB)+11, p11) \
            NMS_STEP((BB)+12, p12) NMS_STEP((BB)+13, p13) NMS_STEP((BB)+14, p14) NMS_STEP((BB)+15, p15)
            NMS_STEP16(0) NMS_STEP16(16) NMS_STEP16(32) NMS_STEP16(48)
#undef NMS_STEP16
#undef NMS_STEP
            int over = nvalid - base;
            if (over < 64) kw &= (over <= 0) ? 0ull : ((1ull << over) - 1ull);
            if (lane == 0) keepw[blk] = kw;
            kept_total += (int)__popcll(kw);
            if (kept_total >= MAX_DET) break;              // rest can't affect first 300
        }
        // extract first <=300 kept slots into LDS
        if (lane < 16) {
            u64 kw = keepw[lane];
            u32 rank = 0;
            for (int m = 0; m < 16; ++m)
                if (m < lane) rank += (u32)__popcll(keepw[m]);
            while (kw) {
                int b = (int)__ffsll((long long)kw) - 1;
                if (rank < MAX_DET) s_sel[rank] = (u32)((lane << 6) + b);
                ++rank;
                kw &= kw - 1;
            }
        }
        if (lane == 0) s_cnt = (u32)min(kept_total, MAX_DET);
    }
    __syncthreads();
    // fused output: all 16 waves write det/valid/logits (d_out is re-poisoned)
    u32 K = s_cnt;
    for (int t = wid; t < MAX_DET; t += 16) {
        bool v = (u32)t < K;
        int slot = v ? (int)s_sel[t] : 0;
        int g = img * TOPK + slot;
        u32 aidx = top_idx[g];
        size_t detoff = ((size_t)img * MAX_DET + t) * 6;
        size_t voff = (size_t)B * MAX_DET * 6 + (size_t)img * MAX_DET + t;
        size_t loff = (size_t)B * MAX_DET * 7 + ((size_t)img * MAX_DET + t) * NCLS;
        const float* lrow = logits + ((size_t)img * NA + aidx) * NCLS;
        out[loff + lane] = v ? lrow[lane] : 0.0f;
        int l2 = lane + 64;
        if (lane < 16)       out[loff + l2] = v ? lrow[l2] : 0.0f;
        else if (lane < 20)  out[detoff + (lane - 16)] = v ? boxk[(size_t)g * 4 + (lane - 16)] : 0.0f;
        else if (lane == 20) out[detoff + 4] = v ? top_score[g] : 0.0f;
        else if (lane == 21) out[detoff + 5] = v ? clsf[g] : 0.0f;
        else if (lane == 22) out[voff] = v ? 1.0f : 0.0f;
    }
}

extern "C" void kernel_launch(void* const* d_in, const int* in_sizes, int n_in,
                              void* d_out, int out_size, void* d_ws, size_t ws_size,
                              hipStream_t stream) {
    const float* pred = (const float*)d_in[0];
    const float* logits = (const float*)d_in[1];
    float* out = (float*)d_out;
    const int B = out_size / (MAX_DET * (6 + 1 + NCLS));   // 16
    const int NA = in_sizes[0] / (B * ROW);                // 25200

    char* p = (char*)d_ws;
    auto alloc = [&](size_t bytes) -> void* {
        void* r = (void*)p;
        p += (bytes + 255) & ~(size_t)255;
        return r;
    };
    u32* key       = (u32*)alloc((size_t)B * NA * 4);
    u32* cls       = (u32*)alloc((size_t)B * NA * 4);
    u32* top_idx   = (u32*)alloc((size_t)B * TOPK * 4);
    float* top_scr = (float*)alloc((size_t)B * TOPK * 4);
    float* boxk    = (float*)alloc((size_t)B * TOPK * 16);
    float* nmsbox  = (float*)alloc((size_t)B * TOPK * 16);
    float* clsf    = (float*)alloc((size_t)B * TOPK * 4);
    u64* mask      = (u64*)alloc((size_t)B * TOPK * 16 * 8);
    u32* dummy     = (u32*)alloc(256);

    k_score<<<dim3((NA + APB - 1) / APB, B), 256, 0, stream>>>(pred, key, cls, NA);
    k_topk<<<dim3(B), 1024, 0, stream>>>(key, pred, cls, top_idx, top_scr,
                                         boxk, nmsbox, clsf, NA);
    k_mask<<<dim3(TOPK / 64, B), 1024, 0, stream>>>(nmsbox, mask);
    k_nms<<<dim3(B), 1024, 0, stream>>>(mask, top_scr, top_idx, boxk, clsf,
                                        logits, out, dummy, NA, B);
}